// Round 1
// baseline (1561.383 us; speedup 1.0000x reference)
//
#include <hip/hip_runtime.h>
#include <hip/hip_bf16.h>

// Sizes for this problem instance
#define B_   2
#define C_   512
#define N_   4096           // 64*64 pixels
#define G_   8              // groups
#define NH_  8              // heads
#define HD_  64             // head dim
#define GRPSZ (C_ / G_)     // 64 channels per group
#define GRPELEMS (GRPSZ * N_)   // 262144 elements per (b, group)

// ---------------------------------------------------------------------------
// Kernel 1: GroupNorm statistics. One block per (b, group). Each group's data
// is a contiguous 64ch x 4096px = 262144-float block in (b, c, h, w) layout.
// ---------------------------------------------------------------------------
__global__ __launch_bounds__(256) void gn_stats(const float* __restrict__ x,
                                                float* __restrict__ stats) {
    __shared__ float ss[256];
    __shared__ float sq[256];
    const int bg = blockIdx.x;  // 0..15
    const float4* p = (const float4*)(x + (size_t)bg * GRPELEMS);
    float s = 0.f, s2 = 0.f;
    for (int i = threadIdx.x; i < GRPELEMS / 4; i += 256) {
        float4 v = p[i];
        s  += v.x + v.y + v.z + v.w;
        s2 += v.x * v.x + v.y * v.y + v.z * v.z + v.w * v.w;
    }
    ss[threadIdx.x] = s;
    sq[threadIdx.x] = s2;
    __syncthreads();
    for (int st = 128; st > 0; st >>= 1) {
        if (threadIdx.x < st) {
            ss[threadIdx.x] += ss[threadIdx.x + st];
            sq[threadIdx.x] += sq[threadIdx.x + st];
        }
        __syncthreads();
    }
    if (threadIdx.x == 0) {
        const float inv = 1.f / (float)GRPELEMS;
        float mean = ss[0] * inv;
        float var  = sq[0] * inv - mean * mean;
        stats[bg]      = mean;
        stats[16 + bg] = rsqrtf(var + 1e-5f);
    }
}

// ---------------------------------------------------------------------------
// Kernel 2: apply GroupNorm affine. float4 per thread.
// ---------------------------------------------------------------------------
__global__ __launch_bounds__(256) void gn_apply(const float* __restrict__ x,
                                                const float* __restrict__ w,
                                                const float* __restrict__ bb,
                                                const float* __restrict__ stats,
                                                float* __restrict__ y) {
    int idx = blockIdx.x * 256 + threadIdx.x;  // float4 index; 1048576 total
    int e = idx << 2;
    int c  = (e >> 12) & (C_ - 1);             // channel
    int bg = (e >> 21) * G_ + (c >> 6);        // e / (512*4096) = b
    float mean = stats[bg], rstd = stats[16 + bg];
    float sc = rstd * w[c];
    float sh = bb[c] - mean * sc;
    float4 v = ((const float4*)x)[idx];
    v.x = v.x * sc + sh;
    v.y = v.y * sc + sh;
    v.z = v.z * sc + sh;
    v.w = v.w * sc + sh;
    ((float4*)y)[idx] = v;
}

// ---------------------------------------------------------------------------
// 1x1-conv GEMM: Y[b][o][p] = sum_c W[o][c] * X[b][c][p] + bias[o] (+resid)
// 64x64 tile, BK=32, 4x4 per-thread microtile, 256 threads.
// W row-major (M_TOTAL x 512), X (b, 512, 4096).
// ---------------------------------------------------------------------------
template <int M_TOTAL, bool RESIDUAL>
__global__ __launch_bounds__(256) void gemm1x1(const float* __restrict__ W,
                                               const float* __restrict__ X,
                                               const float* __restrict__ bias,
                                               const float* __restrict__ resid,
                                               float* __restrict__ Y) {
    const int b  = blockIdx.z;
    const int M0 = blockIdx.y << 6;
    const int N0 = blockIdx.x << 6;
    const int tid = threadIdx.x;
    const int tx = tid & 15, ty = tid >> 4;
    __shared__ float As[32][68];  // [k][m], padded
    __shared__ float Bs[32][68];  // [k][p], padded
    const float* Xb = X + (size_t)b * (C_ * N_);
    float acc[4][4] = {};

    const int mA = tid >> 2;          // 0..63 (output row within tile)
    const int kA = (tid & 3) << 3;    // 0,8,16,24
    const int kB = tid >> 3;          // 0..31
    const int pB = (tid & 7) << 3;    // 0..56

    for (int k0 = 0; k0 < C_; k0 += 32) {
        const float* aSrc = W + (size_t)(M0 + mA) * C_ + k0 + kA;
        float4 a0 = ((const float4*)aSrc)[0];
        float4 a1 = ((const float4*)aSrc)[1];
        const float* bSrc = Xb + (size_t)(k0 + kB) * N_ + N0 + pB;
        float4 b0 = ((const float4*)bSrc)[0];
        float4 b1 = ((const float4*)bSrc)[1];
        As[kA + 0][mA] = a0.x; As[kA + 1][mA] = a0.y;
        As[kA + 2][mA] = a0.z; As[kA + 3][mA] = a0.w;
        As[kA + 4][mA] = a1.x; As[kA + 5][mA] = a1.y;
        As[kA + 6][mA] = a1.z; As[kA + 7][mA] = a1.w;
        *(float4*)&Bs[kB][pB]     = b0;
        *(float4*)&Bs[kB][pB + 4] = b1;
        __syncthreads();
#pragma unroll
        for (int kk = 0; kk < 32; ++kk) {
            float4 a4 = *(const float4*)&As[kk][ty << 2];
            float4 b4 = *(const float4*)&Bs[kk][tx << 2];
            float av[4] = {a4.x, a4.y, a4.z, a4.w};
            float bv[4] = {b4.x, b4.y, b4.z, b4.w};
#pragma unroll
            for (int i = 0; i < 4; ++i)
#pragma unroll
                for (int j = 0; j < 4; ++j) acc[i][j] += av[i] * bv[j];
        }
        __syncthreads();
    }
#pragma unroll
    for (int i = 0; i < 4; ++i) {
        int o = M0 + (ty << 2) + i;
        float bi = bias[o];
        size_t off = ((size_t)b * M_TOTAL + o) * N_ + N0 + (tx << 2);
        float4 r;
        r.x = acc[i][0] + bi;
        r.y = acc[i][1] + bi;
        r.z = acc[i][2] + bi;
        r.w = acc[i][3] + bi;
        if (RESIDUAL) {
            float4 xr = *(const float4*)(resid + off);
            r.x += xr.x; r.y += xr.y; r.z += xr.z; r.w += xr.w;
        }
        *(float4*)(Y + off) = r;
    }
}

// ---------------------------------------------------------------------------
// Flash attention. One block per (b, head, 64-query tile). qkv layout:
// qkv[b][o][p], o = {0:q,512:k,1024:v} + h*64 + d.  S[n,m]=sum_d q[d,n]k[d,m].
// Online softmax over m; P re-distributed via LDS (aliases K tile buffer).
// Output att[b][h*64+d][n].
// ---------------------------------------------------------------------------
__global__ __launch_bounds__(256) void attn_flash(const float* __restrict__ qkv,
                                                  float* __restrict__ att) {
    const int qb = blockIdx.x;   // 0..63 query tile
    const int h  = blockIdx.y;   // 0..7
    const int b  = blockIdx.z;   // 0..1
    const int tid = threadIdx.x;
    const int tx = tid & 15, ty = tid >> 4;

    __shared__ float Qs[64][68];   // [d][nq]  (reused as output tile [d][nq])
    __shared__ float KPs[64][68];  // K tile [d][m]; then P tile [nq][m]
    __shared__ float Vs[64][68];   // V tile [d][m]

    const size_t base = ((size_t)b * (3 * C_) + (size_t)h * HD_) * N_;
    const float* qg = qkv + base;
    const float* kg = qkv + base + (size_t)C_ * N_;
    const float* vg = qkv + base + (size_t)(2 * C_) * N_;
    const int nq0 = qb << 6;

    const int lr = tid >> 2;        // 0..63 row (d)
    const int lc = (tid & 3) << 4;  // 0,16,32,48

    {   // load Q tile [d][nq]
        const float* src = qg + (size_t)lr * N_ + nq0 + lc;
#pragma unroll
        for (int u = 0; u < 4; ++u)
            *(float4*)&Qs[lr][lc + 4 * u] = ((const float4*)src)[u];
    }

    float acc[4][4] = {};           // [nq_i][d_j], d = j*16+tx
    float m_i[4], l_i[4];
#pragma unroll
    for (int i = 0; i < 4; ++i) { m_i[i] = -1e30f; l_i[i] = 0.f; }

    for (int kt = 0; kt < 64; ++kt) {
        __syncthreads();  // previous iteration's LDS reads complete
        {
            const float* ks = kg + (size_t)lr * N_ + (kt << 6) + lc;
            const float* vs = vg + (size_t)lr * N_ + (kt << 6) + lc;
#pragma unroll
            for (int u = 0; u < 4; ++u) {
                *(float4*)&KPs[lr][lc + 4 * u] = ((const float4*)ks)[u];
                *(float4*)&Vs[lr][lc + 4 * u]  = ((const float4*)vs)[u];
            }
        }
        __syncthreads();

        // scores S[nq=ty*4+i][m=tx*4+j]
        float s[4][4] = {};
#pragma unroll 8
        for (int d = 0; d < 64; ++d) {
            float4 q4 = *(const float4*)&Qs[d][ty << 2];
            float4 k4 = *(const float4*)&KPs[d][tx << 2];
            float qv[4] = {q4.x, q4.y, q4.z, q4.w};
            float kv[4] = {k4.x, k4.y, k4.z, k4.w};
#pragma unroll
            for (int i = 0; i < 4; ++i)
#pragma unroll
                for (int j = 0; j < 4; ++j) s[i][j] += qv[i] * kv[j];
        }
#pragma unroll
        for (int i = 0; i < 4; ++i)
#pragma unroll
            for (int j = 0; j < 4; ++j) s[i][j] *= 0.125f;  // hd^-0.5

        // online softmax: rows owned by 16-lane groups (same ty)
        float p[4][4];
#pragma unroll
        for (int i = 0; i < 4; ++i) {
            float rm = fmaxf(fmaxf(s[i][0], s[i][1]), fmaxf(s[i][2], s[i][3]));
            rm = fmaxf(rm, __shfl_xor(rm, 1));
            rm = fmaxf(rm, __shfl_xor(rm, 2));
            rm = fmaxf(rm, __shfl_xor(rm, 4));
            rm = fmaxf(rm, __shfl_xor(rm, 8));
            float mn = fmaxf(m_i[i], rm);
            float alpha = __expf(m_i[i] - mn);
            float rs = 0.f;
#pragma unroll
            for (int j = 0; j < 4; ++j) { p[i][j] = __expf(s[i][j] - mn); rs += p[i][j]; }
            rs += __shfl_xor(rs, 1);
            rs += __shfl_xor(rs, 2);
            rs += __shfl_xor(rs, 4);
            rs += __shfl_xor(rs, 8);
            l_i[i] = l_i[i] * alpha + rs;
            m_i[i] = mn;
#pragma unroll
            for (int j = 0; j < 4; ++j) acc[i][j] *= alpha;
        }

        __syncthreads();  // all K reads done; safe to overwrite with P
#pragma unroll
        for (int i = 0; i < 4; ++i)
            *(float4*)&KPs[(ty << 2) + i][tx << 2] =
                make_float4(p[i][0], p[i][1], p[i][2], p[i][3]);
        __syncthreads();

        // acc[nq][d] += sum_m P[nq][m] * V[d][m];   d = j*16+tx (2-way bank alias: free)
#pragma unroll 4
        for (int mq = 0; mq < 16; ++mq) {
            float4 p4[4], v4[4];
#pragma unroll
            for (int i = 0; i < 4; ++i) p4[i] = *(const float4*)&KPs[(ty << 2) + i][mq << 2];
#pragma unroll
            for (int j = 0; j < 4; ++j) v4[j] = *(const float4*)&Vs[(j << 4) + tx][mq << 2];
#pragma unroll
            for (int i = 0; i < 4; ++i)
#pragma unroll
                for (int j = 0; j < 4; ++j)
                    acc[i][j] += p4[i].x * v4[j].x + p4[i].y * v4[j].y +
                                 p4[i].z * v4[j].z + p4[i].w * v4[j].w;
        }
    }

    // epilogue: out[d][nq] = acc/l staged through LDS for coalesced store
    __syncthreads();
#pragma unroll
    for (int j = 0; j < 4; ++j) {
        float4 o4 = make_float4(acc[0][j] / l_i[0], acc[1][j] / l_i[1],
                                acc[2][j] / l_i[2], acc[3][j] / l_i[3]);
        *(float4*)&Qs[(j << 4) + tx][ty << 2] = o4;
    }
    __syncthreads();
    {
        float* dst = att + ((size_t)b * C_ + (size_t)h * HD_ + lr) * N_ + nq0 + lc;
#pragma unroll
        for (int u = 0; u < 4; ++u)
            ((float4*)dst)[u] = *(const float4*)&Qs[lr][lc + 4 * u];
    }
}

// ---------------------------------------------------------------------------
extern "C" void kernel_launch(void* const* d_in, const int* in_sizes, int n_in,
                              void* d_out, int out_size, void* d_ws, size_t ws_size,
                              hipStream_t stream) {
    const float* x      = (const float*)d_in[0];
    const float* norm_w = (const float*)d_in[1];
    const float* norm_b = (const float*)d_in[2];
    const float* qkv_w  = (const float*)d_in[3];
    const float* qkv_b  = (const float*)d_in[4];
    const float* proj_w = (const float*)d_in[5];
    const float* proj_b = (const float*)d_in[6];
    float* out = (float*)d_out;

    float* ws    = (float*)d_ws;
    float* stats = ws;                       // 64 floats (mean[16], rstd[16])
    float* xn    = ws + 64;                  // 2*512*4096 = 4194304
    float* qkv   = xn + (size_t)B_ * C_ * N_;        // 3*2*512*4096 = 12582912
    float* att   = qkv + (size_t)B_ * 3 * C_ * N_;   // 4194304

    gn_stats<<<B_ * G_, 256, 0, stream>>>(x, stats);
    gn_apply<<<(B_ * C_ * N_ / 4) / 256, 256, 0, stream>>>(x, norm_w, norm_b, stats, xn);
    gemm1x1<3 * C_, false><<<dim3(N_ / 64, 3 * C_ / 64, B_), 256, 0, stream>>>(
        qkv_w, xn, qkv_b, nullptr, qkv);
    attn_flash<<<dim3(N_ / 64, NH_, B_), 256, 0, stream>>>(qkv, att);
    gemm1x1<C_, true><<<dim3(N_ / 64, C_ / 64, B_), 256, 0, stream>>>(
        proj_w, att, proj_b, x, out);
}

// Round 2
// 546.683 us; speedup vs baseline: 2.8561x; 2.8561x over previous
//
#include <hip/hip_runtime.h>
#include <stdint.h>

#define B_   2
#define C_   512
#define N_   4096           // 64*64 pixels
#define G_   8
#define NH_  8
#define HD_  64
#define GRPELEMS ((C_ / G_) * N_)   // 262144 per (b, group)

typedef __bf16 bf16x8 __attribute__((ext_vector_type(8)));
typedef float  f32x4  __attribute__((ext_vector_type(4)));

#if __has_builtin(__builtin_amdgcn_exp2f)
#define EXP2(x) __builtin_amdgcn_exp2f(x)
#else
#define EXP2(x) exp2f(x)
#endif

// fp32 -> bf16 round-to-nearest-even, bit trick (finite inputs only)
__device__ inline unsigned f2bf(float f) {
    union { float f; unsigned u; } v; v.f = f;
    return (v.u + 0x7FFFu + ((v.u >> 16) & 1u)) >> 16;
}

// ---------------------------------------------------------------------------
// GroupNorm stats: one block per (b, group); group = contiguous 256 KB.
// ---------------------------------------------------------------------------
__global__ __launch_bounds__(256) void gn_stats(const float* __restrict__ x,
                                                float* __restrict__ stats) {
    __shared__ float ss[256];
    __shared__ float sq[256];
    const int bg = blockIdx.x;  // 0..15
    const float4* p = (const float4*)(x + (size_t)bg * GRPELEMS);
    float s = 0.f, s2 = 0.f;
    for (int i = threadIdx.x; i < GRPELEMS / 4; i += 256) {
        float4 v = p[i];
        s  += v.x + v.y + v.z + v.w;
        s2 += v.x * v.x + v.y * v.y + v.z * v.z + v.w * v.w;
    }
    ss[threadIdx.x] = s;
    sq[threadIdx.x] = s2;
    __syncthreads();
    for (int st = 128; st > 0; st >>= 1) {
        if (threadIdx.x < st) {
            ss[threadIdx.x] += ss[threadIdx.x + st];
            sq[threadIdx.x] += sq[threadIdx.x + st];
        }
        __syncthreads();
    }
    if (threadIdx.x == 0) {
        const float inv = 1.f / (float)GRPELEMS;
        float mean = ss[0] * inv;
        float var  = sq[0] * inv - mean * mean;
        stats[bg]      = mean;
        stats[16 + bg] = rsqrtf(var + 1e-5f);
    }
}

__global__ __launch_bounds__(256) void gn_apply(const float* __restrict__ x,
                                                const float* __restrict__ w,
                                                const float* __restrict__ bb,
                                                const float* __restrict__ stats,
                                                float* __restrict__ y) {
    int idx = blockIdx.x * 256 + threadIdx.x;
    int e = idx << 2;
    int c  = (e >> 12) & (C_ - 1);
    int bg = (e >> 21) * G_ + (c >> 6);
    float mean = stats[bg], rstd = stats[16 + bg];
    float sc = rstd * w[c];
    float sh = bb[c] - mean * sc;
    float4 v = ((const float4*)x)[idx];
    v.x = v.x * sc + sh;
    v.y = v.y * sc + sh;
    v.z = v.z * sc + sh;
    v.w = v.w * sc + sh;
    ((float4*)y)[idx] = v;
}

// ---------------------------------------------------------------------------
// QKV GEMM (fp32 compute): Y[o][p] = sum_c W[o][c] X[b][c][p] + bias.
// Epilogue writes bf16 in attention layouts:
//   q (o<512):    qT[b][h][p][d]  scaled by 0.125*log2(e)
//   k (512..1023): kT[b][h][p][d]
//   v (1024..):    vB[b][h][d][p]
// ---------------------------------------------------------------------------
__global__ __launch_bounds__(256) void gemm_qkv(const float* __restrict__ W,
                                                const float* __restrict__ X,
                                                const float* __restrict__ bias,
                                                __bf16* __restrict__ qT,
                                                __bf16* __restrict__ kT,
                                                __bf16* __restrict__ vB) {
    const int b  = blockIdx.z;
    const int M0 = blockIdx.y << 6;
    const int N0 = blockIdx.x << 6;
    const int tid = threadIdx.x;
    const int tx = tid & 15, ty = tid >> 4;
    __shared__ float As[32][68];
    __shared__ float Bs[32][68];
    const float* Xb = X + (size_t)b * (C_ * N_);
    float acc[4][4] = {};

    const int mA = tid >> 2;
    const int kA = (tid & 3) << 3;
    const int kB = tid >> 3;
    const int pB = (tid & 7) << 3;

    for (int k0 = 0; k0 < C_; k0 += 32) {
        const float* aSrc = W + (size_t)(M0 + mA) * C_ + k0 + kA;
        float4 a0 = ((const float4*)aSrc)[0];
        float4 a1 = ((const float4*)aSrc)[1];
        const float* bSrc = Xb + (size_t)(k0 + kB) * N_ + N0 + pB;
        float4 b0 = ((const float4*)bSrc)[0];
        float4 b1 = ((const float4*)bSrc)[1];
        As[kA + 0][mA] = a0.x; As[kA + 1][mA] = a0.y;
        As[kA + 2][mA] = a0.z; As[kA + 3][mA] = a0.w;
        As[kA + 4][mA] = a1.x; As[kA + 5][mA] = a1.y;
        As[kA + 6][mA] = a1.z; As[kA + 7][mA] = a1.w;
        *(float4*)&Bs[kB][pB]     = b0;
        *(float4*)&Bs[kB][pB + 4] = b1;
        __syncthreads();
#pragma unroll
        for (int kk = 0; kk < 32; ++kk) {
            float4 a4 = *(const float4*)&As[kk][ty << 2];
            float4 b4 = *(const float4*)&Bs[kk][tx << 2];
            float av[4] = {a4.x, a4.y, a4.z, a4.w};
            float bv[4] = {b4.x, b4.y, b4.z, b4.w};
#pragma unroll
            for (int i = 0; i < 4; ++i)
#pragma unroll
                for (int j = 0; j < 4; ++j) acc[i][j] += av[i] * bv[j];
        }
        __syncthreads();
    }

    const int t = M0 >> 9;            // 0=q 1=k 2=v
    const int h = (M0 >> 6) & 7;
    const size_t bh = (size_t)b * NH_ + h;
    float bi[4];
#pragma unroll
    for (int i = 0; i < 4; ++i) bi[i] = bias[M0 + (ty << 2) + i];

    if (t == 2) {  // v: [d][p], pack 4 consecutive p
        __bf16* dst = vB + bh * (HD_ * N_);
#pragma unroll
        for (int i = 0; i < 4; ++i) {
            int d = (ty << 2) + i;
            unsigned lo = f2bf(acc[i][0] + bi[i]) | (f2bf(acc[i][1] + bi[i]) << 16);
            unsigned hi = f2bf(acc[i][2] + bi[i]) | (f2bf(acc[i][3] + bi[i]) << 16);
            uint2 pk; pk.x = lo; pk.y = hi;
            *(uint2*)(dst + (size_t)d * N_ + N0 + (tx << 2)) = pk;
        }
    } else {       // q/k: [p][d], pack 4 consecutive d
        const float scale = (t == 0) ? (0.125f * 1.44269504f) : 1.f;
        __bf16* dst = (t == 0 ? qT : kT) + bh * ((size_t)N_ * HD_);
#pragma unroll
        for (int j = 0; j < 4; ++j) {
            int p = N0 + (tx << 2) + j;
            unsigned lo = f2bf((acc[0][j] + bi[0]) * scale) |
                          (f2bf((acc[1][j] + bi[1]) * scale) << 16);
            unsigned hi = f2bf((acc[2][j] + bi[2]) * scale) |
                          (f2bf((acc[3][j] + bi[3]) * scale) << 16);
            uint2 pk; pk.x = lo; pk.y = hi;
            *(uint2*)(dst + (size_t)p * HD_ + (ty << 2)) = pk;
        }
    }
}

// ---------------------------------------------------------------------------
// MFMA flash attention. wg = 4 waves x 32 queries = 128 q; k-tile = 64 keys.
// S^T = K * Q^T  (A = K[key][d] from LDS, B = Q^T in regs)  -> D col=q, row=key
// O^T = V^T * P^T (A = V[d][key] from LDS, B = P^T via per-wave LDS buffer)
// Layout facts (m89/m91/m120): A/B idx16 = lane&15, k = quad*8+j;
//                              C/D col = lane&15, row = quad*4+reg.
// q pre-scaled by 0.125*log2e -> softmax uses exp2 directly.
// ---------------------------------------------------------------------------
__global__ __launch_bounds__(256) void attn_mfma(const __bf16* __restrict__ qT,
                                                 const __bf16* __restrict__ kT,
                                                 const __bf16* __restrict__ vB,
                                                 float* __restrict__ att) {
    const int tid  = threadIdx.x;
    const int w    = tid >> 6;
    const int lane = tid & 63;
    const int quad = lane >> 4;
    const int l16  = lane & 15;
    const int h = blockIdx.y, b = blockIdx.z;
    const int nq0 = blockIdx.x << 7;      // 128 q per wg
    const int qw0 = nq0 + (w << 5);       // 32 q per wave

    __shared__ __bf16 Ks[64][72];         // [key][d], +8 pad -> 2-way alias only
    __shared__ __bf16 Vs[64][72];         // [d][key]
    __shared__ __bf16 Ps[4][32][72];      // per-wave P^T as [q][key]

    const size_t bh = (size_t)b * NH_ + h;
    const __bf16* qTb = qT + bh * ((size_t)N_ * HD_);
    const __bf16* kTb = kT + bh * ((size_t)N_ * HD_);
    const __bf16* vBb = vB + bh * ((size_t)HD_ * N_);

    // Q fragments: persistent across the whole k-loop
    bf16x8 qf[2][2];
#pragma unroll
    for (int qt = 0; qt < 2; ++qt)
#pragma unroll
        for (int hh = 0; hh < 2; ++hh)
            qf[qt][hh] = *(const bf16x8*)(qTb +
                (size_t)(qw0 + (qt << 4) + l16) * HD_ + (hh << 5) + (quad << 3));

    const f32x4 zero4 = {0.f, 0.f, 0.f, 0.f};
    f32x4 o[4][2];
#pragma unroll
    for (int dt = 0; dt < 4; ++dt) { o[dt][0] = zero4; o[dt][1] = zero4; }
    float m_i[2] = {-1e30f, -1e30f}, l_i[2] = {0.f, 0.f};

    const int sr = tid >> 2;            // staging row 0..63
    const int sc = (tid & 3) << 4;      // staging col {0,16,32,48}

    for (int it = 0; it < 64; ++it) {
        const int kb = it << 6;
        {   // stage K[key][d] and V[d][key] tiles (bf16, 8 KB each)
            const float4* ksrc = (const float4*)(kTb + (size_t)(kb + sr) * HD_ + sc);
            const float4* vsrc = (const float4*)(vBb + (size_t)sr * N_ + kb + sc);
            float4 k0 = ksrc[0], k1 = ksrc[1];
            float4 v0 = vsrc[0], v1 = vsrc[1];
            *(float4*)&Ks[sr][sc]     = k0;
            *(float4*)&Ks[sr][sc + 8] = k1;
            *(float4*)&Vs[sr][sc]     = v0;
            *(float4*)&Vs[sr][sc + 8] = v1;
        }
        __syncthreads();

        // S^T[key][q]: 4 key-tiles x 2 q-tiles, K-dim = 64 d in 2 halves
        f32x4 s[4][2];
#pragma unroll
        for (int kt = 0; kt < 4; ++kt) { s[kt][0] = zero4; s[kt][1] = zero4; }
#pragma unroll
        for (int hh = 0; hh < 2; ++hh) {
#pragma unroll
            for (int kt = 0; kt < 4; ++kt) {
                bf16x8 a = *(const bf16x8*)&Ks[(kt << 4) + l16][(hh << 5) + (quad << 3)];
                s[kt][0] = __builtin_amdgcn_mfma_f32_16x16x32_bf16(a, qf[0][hh], s[kt][0], 0, 0, 0);
                s[kt][1] = __builtin_amdgcn_mfma_f32_16x16x32_bf16(a, qf[1][hh], s[kt][1], 0, 0, 0);
            }
        }

        // online softmax per q-tile (lane owns query qt*16+l16; keys split
        // across regs (quad*4+reg within kt-tile) and quads -> shfl 16,32)
#pragma unroll
        for (int qt = 0; qt < 2; ++qt) {
            float mx = s[0][qt][0];
#pragma unroll
            for (int kt = 0; kt < 4; ++kt)
#pragma unroll
                for (int r = 0; r < 4; ++r) mx = fmaxf(mx, s[kt][qt][r]);
            mx = fmaxf(mx, __shfl_xor(mx, 16));
            mx = fmaxf(mx, __shfl_xor(mx, 32));
            float mn = fmaxf(m_i[qt], mx);
            float alpha = EXP2(m_i[qt] - mn);
            m_i[qt] = mn;
            float rs = 0.f;
#pragma unroll
            for (int kt = 0; kt < 4; ++kt)
#pragma unroll
                for (int r = 0; r < 4; ++r) {
                    float pv = EXP2(s[kt][qt][r] - mn);
                    s[kt][qt][r] = pv;
                    rs += pv;
                }
            rs += __shfl_xor(rs, 16);
            rs += __shfl_xor(rs, 32);
            l_i[qt] = l_i[qt] * alpha + rs;
#pragma unroll
            for (int dt = 0; dt < 4; ++dt) o[dt][qt] *= alpha;
            // pack P^T -> per-wave LDS [q][key]
#pragma unroll
            for (int kt = 0; kt < 4; ++kt) {
                unsigned lo = f2bf(s[kt][qt][0]) | (f2bf(s[kt][qt][1]) << 16);
                unsigned hi = f2bf(s[kt][qt][2]) | (f2bf(s[kt][qt][3]) << 16);
                uint2 pk; pk.x = lo; pk.y = hi;
                *(uint2*)&Ps[w][(qt << 4) + l16][(kt << 4) + (quad << 2)] = pk;
            }
        }

        // O^T[d][q] += V^T[d][key] * P^T[key][q]
#pragma unroll
        for (int hh = 0; hh < 2; ++hh) {
            bf16x8 pf0 = *(const bf16x8*)&Ps[w][l16][(hh << 5) + (quad << 3)];
            bf16x8 pf1 = *(const bf16x8*)&Ps[w][16 + l16][(hh << 5) + (quad << 3)];
#pragma unroll
            for (int dt = 0; dt < 4; ++dt) {
                bf16x8 a = *(const bf16x8*)&Vs[(dt << 4) + l16][(hh << 5) + (quad << 3)];
                o[dt][0] = __builtin_amdgcn_mfma_f32_16x16x32_bf16(a, pf0, o[dt][0], 0, 0, 0);
                o[dt][1] = __builtin_amdgcn_mfma_f32_16x16x32_bf16(a, pf1, o[dt][1], 0, 0, 0);
            }
        }
        __syncthreads();  // K/V reads done before next stage overwrites
    }

    // epilogue: att[b][h*64+d][n] = o / l
    float* attb = att + ((size_t)b * C_ + (size_t)h * HD_) * N_;
#pragma unroll
    for (int qt = 0; qt < 2; ++qt) {
        float inv = 1.f / l_i[qt];
        int n = qw0 + (qt << 4) + l16;
#pragma unroll
        for (int dt = 0; dt < 4; ++dt)
#pragma unroll
            for (int r = 0; r < 4; ++r)
                attb[(size_t)((dt << 4) + (quad << 2) + r) * N_ + n] = o[dt][qt][r] * inv;
    }
}

// ---------------------------------------------------------------------------
// Proj GEMM (fp32) + bias + residual -> d_out
// ---------------------------------------------------------------------------
__global__ __launch_bounds__(256) void gemm_proj(const float* __restrict__ W,
                                                 const float* __restrict__ X,
                                                 const float* __restrict__ bias,
                                                 const float* __restrict__ resid,
                                                 float* __restrict__ Y) {
    const int b  = blockIdx.z;
    const int M0 = blockIdx.y << 6;
    const int N0 = blockIdx.x << 6;
    const int tid = threadIdx.x;
    const int tx = tid & 15, ty = tid >> 4;
    __shared__ float As[32][68];
    __shared__ float Bs[32][68];
    const float* Xb = X + (size_t)b * (C_ * N_);
    float acc[4][4] = {};

    const int mA = tid >> 2;
    const int kA = (tid & 3) << 3;
    const int kB = tid >> 3;
    const int pB = (tid & 7) << 3;

    for (int k0 = 0; k0 < C_; k0 += 32) {
        const float* aSrc = W + (size_t)(M0 + mA) * C_ + k0 + kA;
        float4 a0 = ((const float4*)aSrc)[0];
        float4 a1 = ((const float4*)aSrc)[1];
        const float* bSrc = Xb + (size_t)(k0 + kB) * N_ + N0 + pB;
        float4 b0 = ((const float4*)bSrc)[0];
        float4 b1 = ((const float4*)bSrc)[1];
        As[kA + 0][mA] = a0.x; As[kA + 1][mA] = a0.y;
        As[kA + 2][mA] = a0.z; As[kA + 3][mA] = a0.w;
        As[kA + 4][mA] = a1.x; As[kA + 5][mA] = a1.y;
        As[kA + 6][mA] = a1.z; As[kA + 7][mA] = a1.w;
        *(float4*)&Bs[kB][pB]     = b0;
        *(float4*)&Bs[kB][pB + 4] = b1;
        __syncthreads();
#pragma unroll
        for (int kk = 0; kk < 32; ++kk) {
            float4 a4 = *(const float4*)&As[kk][ty << 2];
            float4 b4 = *(const float4*)&Bs[kk][tx << 2];
            float av[4] = {a4.x, a4.y, a4.z, a4.w};
            float bv[4] = {b4.x, b4.y, b4.z, b4.w};
#pragma unroll
            for (int i = 0; i < 4; ++i)
#pragma unroll
                for (int j = 0; j < 4; ++j) acc[i][j] += av[i] * bv[j];
        }
        __syncthreads();
    }
#pragma unroll
    for (int i = 0; i < 4; ++i) {
        int o = M0 + (ty << 2) + i;
        float bi = bias[o];
        size_t off = ((size_t)b * C_ + o) * N_ + N0 + (tx << 2);
        float4 r;
        r.x = acc[i][0] + bi;
        r.y = acc[i][1] + bi;
        r.z = acc[i][2] + bi;
        r.w = acc[i][3] + bi;
        float4 xr = *(const float4*)(resid + off);
        r.x += xr.x; r.y += xr.y; r.z += xr.z; r.w += xr.w;
        *(float4*)(Y + off) = r;
    }
}

// ---------------------------------------------------------------------------
extern "C" void kernel_launch(void* const* d_in, const int* in_sizes, int n_in,
                              void* d_out, int out_size, void* d_ws, size_t ws_size,
                              hipStream_t stream) {
    const float* x      = (const float*)d_in[0];
    const float* norm_w = (const float*)d_in[1];
    const float* norm_b = (const float*)d_in[2];
    const float* qkv_w  = (const float*)d_in[3];
    const float* qkv_b  = (const float*)d_in[4];
    const float* proj_w = (const float*)d_in[5];
    const float* proj_b = (const float*)d_in[6];
    float* out = (float*)d_out;

    const size_t BCN = (size_t)B_ * C_ * N_;      // 4194304
    float* ws    = (float*)d_ws;
    float* stats = ws;                            // 64 floats
    float* xn    = ws + 64;                       // fp32, BCN
    float* att   = xn + BCN;                      // fp32, BCN
    __bf16* qT   = (__bf16*)(att + BCN);          // bf16, BCN  [b][h][p][d]
    __bf16* kT   = qT + BCN;                      // bf16, BCN  [b][h][p][d]
    __bf16* vB   = kT + BCN;                      // bf16, BCN  [b][h][d][p]

    gn_stats<<<B_ * G_, 256, 0, stream>>>(x, stats);
    gn_apply<<<(BCN / 4) / 256, 256, 0, stream>>>(x, norm_w, norm_b, stats, xn);
    gemm_qkv<<<dim3(N_ / 64, 3 * C_ / 64, B_), 256, 0, stream>>>(
        qkv_w, xn, qkv_b, qT, kT, vB);
    attn_mfma<<<dim3(N_ / 128, NH_, B_), 256, 0, stream>>>(qT, kT, vB, att);
    gemm_proj<<<dim3(N_ / 64, C_ / 64, B_), 256, 0, stream>>>(
        proj_w, att, proj_b, x, out);
}

// Round 3
// 348.681 us; speedup vs baseline: 4.4780x; 1.5679x over previous
//
#include <hip/hip_runtime.h>
#include <stdint.h>

#define B_   2
#define C_   512
#define N_   4096           // 64*64 pixels
#define G_   8
#define NH_  8
#define HD_  64
#define GRPELEMS ((C_ / G_) * N_)   // 262144 per (b, group)

typedef __bf16 bf16x8 __attribute__((ext_vector_type(8)));
typedef float  f32x4  __attribute__((ext_vector_type(4)));

#if __has_builtin(__builtin_amdgcn_exp2f)
#define EXP2(x) __builtin_amdgcn_exp2f(x)
#else
#define EXP2(x) exp2f(x)
#endif

// fp32 -> bf16 round-to-nearest-even (finite inputs only)
__device__ inline unsigned f2bf(float f) {
    union { float f; unsigned u; } v; v.f = f;
    return (v.u + 0x7FFFu + ((v.u >> 16) & 1u)) >> 16;
}
__device__ inline __bf16 tobf(float f) {
    unsigned short u = (unsigned short)f2bf(f);
    union { unsigned short u; __bf16 b; } c; c.u = u;
    return c.b;
}

// async global->LDS, 16B per lane; LDS dest = wave-uniform base + lane*16
#define GLOAD16(g, l)                                                     \
    __builtin_amdgcn_global_load_lds(                                     \
        (const __attribute__((address_space(1))) unsigned*)(g),           \
        (__attribute__((address_space(3))) unsigned*)(l), 16, 0, 0)

// ---------------------------------------------------------------------------
// GroupNorm stats: one block per (b, group); group = contiguous 256K floats.
// ---------------------------------------------------------------------------
__global__ __launch_bounds__(256) void gn_stats(const float* __restrict__ x,
                                                float* __restrict__ stats) {
    __shared__ float ss[256];
    __shared__ float sq[256];
    const int bg = blockIdx.x;  // 0..15
    const float4* p = (const float4*)(x + (size_t)bg * GRPELEMS);
    float s = 0.f, s2 = 0.f;
    for (int i = threadIdx.x; i < GRPELEMS / 4; i += 256) {
        float4 v = p[i];
        s  += v.x + v.y + v.z + v.w;
        s2 += v.x * v.x + v.y * v.y + v.z * v.z + v.w * v.w;
    }
    ss[threadIdx.x] = s;
    sq[threadIdx.x] = s2;
    __syncthreads();
    for (int st = 128; st > 0; st >>= 1) {
        if (threadIdx.x < st) {
            ss[threadIdx.x] += ss[threadIdx.x + st];
            sq[threadIdx.x] += sq[threadIdx.x + st];
        }
        __syncthreads();
    }
    if (threadIdx.x == 0) {
        const float inv = 1.f / (float)GRPELEMS;
        float mean = ss[0] * inv;
        float var  = sq[0] * inv - mean * mean;
        stats[bg]      = mean;
        stats[16 + bg] = rsqrtf(var + 1e-5f);
    }
}

// ---------------------------------------------------------------------------
// Weight fp32 -> bf16 (qkv_w then proj_w). 4 elems/thread.
// ---------------------------------------------------------------------------
__global__ __launch_bounds__(256) void w2bf(const float* __restrict__ qw,
                                            const float* __restrict__ pw,
                                            __bf16* __restrict__ dq,
                                            __bf16* __restrict__ dp) {
    const int QW4 = (3 * C_ * C_) / 4;   // 196608
    int idx = blockIdx.x * 256 + threadIdx.x;
    float4 v; __bf16* dst; int o;
    if (idx < QW4) { v = ((const float4*)qw)[idx]; dst = dq; o = idx; }
    else           { v = ((const float4*)pw)[idx - QW4]; dst = dp; o = idx - QW4; }
    uint2 pk;
    pk.x = f2bf(v.x) | (f2bf(v.y) << 16);
    pk.y = f2bf(v.z) | (f2bf(v.w) << 16);
    *(uint2*)(dst + (size_t)o * 4) = pk;
}

// ---------------------------------------------------------------------------
// GroupNorm apply + transpose: x[b][c][p] fp32 -> xnT[b][p][c] bf16.
// 64x64 tile per block; group stats uniform per block (64 ch per group).
// ---------------------------------------------------------------------------
__global__ __launch_bounds__(256) void gn_apply_t(const float* __restrict__ x,
                                                  const float* __restrict__ w,
                                                  const float* __restrict__ bb,
                                                  const float* __restrict__ stats,
                                                  __bf16* __restrict__ xnT) {
    const int p0 = blockIdx.x << 6, c0 = blockIdx.y << 6, b = blockIdx.z;
    __shared__ __bf16 T[64][76];   // row stride 152 B (multiple of 8)
    const int tr  = threadIdx.x >> 4;         // 0..15
    const int tc4 = (threadIdx.x & 15) << 2;  // 0..60
    const int bg = b * G_ + (c0 >> 6);
    const float mean = stats[bg], rstd = stats[16 + bg];
    const float* xb = x + ((size_t)b * C_ + c0) * N_ + p0;
#pragma unroll
    for (int cc = tr; cc < 64; cc += 16) {
        int c = c0 + cc;
        float sc = rstd * w[c];
        float sh = bb[c] - mean * sc;
        float4 v = *(const float4*)(xb + (size_t)cc * N_ + tc4);
        T[tc4 + 0][cc] = tobf(v.x * sc + sh);
        T[tc4 + 1][cc] = tobf(v.y * sc + sh);
        T[tc4 + 2][cc] = tobf(v.z * sc + sh);
        T[tc4 + 3][cc] = tobf(v.w * sc + sh);
    }
    __syncthreads();
    __bf16* dst = xnT + ((size_t)b * N_ + p0) * C_ + c0;
#pragma unroll
    for (int pp = tr; pp < 64; pp += 16)
        *(uint2*)(dst + (size_t)pp * C_ + tc4) = *(const uint2*)&T[pp][tc4];
}

// ---------------------------------------------------------------------------
// bf16 MFMA GEMM: C[o][p] = sum_c A[o][c] * Bm[b][p][c]   (both k-contiguous)
// 128x128 tile, BK=64, 4 waves (2x2), each wave 4x4 16x16x32 MFMA tiles.
// Staging via global_load_lds w=16 with XOR-swizzled 16B granules (applied to
// the GLOBAL address so the wave-uniform LDS-dest constraint holds; ds_read
// then lands on the free 2-way bank alias).
// EPI 0: qkv epilogue -> qT/kT[bh][p][d] (q pre-scaled), vB[bh][d][p], bf16.
// EPI 1: proj epilogue -> Y = C + bias + resid, fp32.
// ---------------------------------------------------------------------------
template <int M_TOTAL, int EPI>
__global__ __launch_bounds__(256) void gemm_bf16(const __bf16* __restrict__ A,
                                                 const __bf16* __restrict__ Bm,
                                                 const float* __restrict__ bias,
                                                 const float* __restrict__ resid,
                                                 __bf16* __restrict__ qT,
                                                 __bf16* __restrict__ kT,
                                                 __bf16* __restrict__ vB,
                                                 float* __restrict__ Y) {
    const int b  = blockIdx.z;
    const int M0 = blockIdx.y << 7;
    const int N0 = blockIdx.x << 7;
    const int tid = threadIdx.x;
    const int w = tid >> 6, lane = tid & 63;
    const int quad = lane >> 4, l16 = lane & 15;
    const int wr = w >> 1, wc = w & 1;

    __shared__ __bf16 As[128 * 64];   // [m][k] tile, 16 KB, XOR-swizzled
    __shared__ __bf16 Bs[128 * 64];   // [n][k] tile

    const __bf16* Bb = Bm + (size_t)b * ((size_t)N_ * C_);

    const int srow = lane >> 3;   // 0..7
    const int sg   = lane & 7;    // 16B granule within 128B row

    f32x4 acc[4][4];
#pragma unroll
    for (int mt = 0; mt < 4; ++mt)
#pragma unroll
        for (int nt = 0; nt < 4; ++nt) acc[mt][nt] = (f32x4){0.f, 0.f, 0.f, 0.f};

    for (int k0 = 0; k0 < C_; k0 += 64) {
        __syncthreads();   // prior ds_reads complete before overwrite
#pragma unroll
        for (int i = 0; i < 4; ++i) {
            int r  = (w << 5) + (i << 3) + srow;              // tile row 0..127
            int gc = ((sg ^ (r & 7)) << 3);                   // swizzled k-elem
            const __bf16* ga = A  + (size_t)(M0 + r) * C_ + k0 + gc;
            const __bf16* gb = Bb + (size_t)(N0 + r) * C_ + k0 + gc;
            GLOAD16(ga, As + (((w << 2) + i) << 9));
            GLOAD16(gb, Bs + (((w << 2) + i) << 9));
        }
        __syncthreads();   // vmcnt(0) drain: staged tiles visible

#pragma unroll
        for (int kk = 0; kk < 2; ++kk) {
            bf16x8 af[4], bfr[4];
            const int gk = (kk << 2) + quad;   // k granule 0..7
#pragma unroll
            for (int mt = 0; mt < 4; ++mt) {
                int m = (wr << 6) + (mt << 4) + l16;
                af[mt] = *(const bf16x8*)&As[(m << 6) + ((gk ^ (m & 7)) << 3)];
            }
#pragma unroll
            for (int nt = 0; nt < 4; ++nt) {
                int n = (wc << 6) + (nt << 4) + l16;
                bfr[nt] = *(const bf16x8*)&Bs[(n << 6) + ((gk ^ (n & 7)) << 3)];
            }
#pragma unroll
            for (int mt = 0; mt < 4; ++mt)
#pragma unroll
                for (int nt = 0; nt < 4; ++nt)
                    acc[mt][nt] = __builtin_amdgcn_mfma_f32_16x16x32_bf16(
                        af[mt], bfr[nt], acc[mt][nt], 0, 0, 0);
        }
    }

    if (EPI == 0) {
        const int t = M0 >> 9;                 // 0=q 1=k 2=v (uniform per block)
        const float sc = (t == 0) ? (0.125f * 1.44269504f) : 1.f;
#pragma unroll
        for (int mt = 0; mt < 4; ++mt) {
            const int o0 = M0 + (wr << 6) + (mt << 4) + (quad << 2);
            const int h  = (o0 >> 6) & 7;
            const int d0 = o0 & 63;
            const size_t bh = (size_t)b * NH_ + h;
            float bi[4];
#pragma unroll
            for (int r = 0; r < 4; ++r) bi[r] = bias[o0 + r];
            if (t < 2) {
                __bf16* dst = (t == 0 ? qT : kT) + (bh * N_) * HD_ + d0;
#pragma unroll
                for (int nt = 0; nt < 4; ++nt) {
                    int p = N0 + (wc << 6) + (nt << 4) + l16;
                    f32x4 v = acc[mt][nt];
                    uint2 pk;
                    pk.x = f2bf((v[0] + bi[0]) * sc) | (f2bf((v[1] + bi[1]) * sc) << 16);
                    pk.y = f2bf((v[2] + bi[2]) * sc) | (f2bf((v[3] + bi[3]) * sc) << 16);
                    *(uint2*)(dst + (size_t)p * HD_) = pk;
                }
            } else {
                __bf16* dst = vB + bh * ((size_t)HD_ * N_);
#pragma unroll
                for (int nt = 0; nt < 4; ++nt) {
                    int p = N0 + (wc << 6) + (nt << 4) + l16;
                    f32x4 v = acc[mt][nt];
#pragma unroll
                    for (int r = 0; r < 4; ++r)
                        dst[(size_t)(d0 + r) * N_ + p] = tobf(v[r] + bi[r]);
                }
            }
        }
    } else {
#pragma unroll
        for (int mt = 0; mt < 4; ++mt) {
            const int o0 = M0 + (wr << 6) + (mt << 4) + (quad << 2);
            float bi[4];
#pragma unroll
            for (int r = 0; r < 4; ++r) bi[r] = bias[o0 + r];
#pragma unroll
            for (int nt = 0; nt < 4; ++nt) {
                int p = N0 + (wc << 6) + (nt << 4) + l16;
                f32x4 v = acc[mt][nt];
#pragma unroll
                for (int r = 0; r < 4; ++r) {
                    size_t off = ((size_t)b * C_ + o0 + r) * N_ + p;
                    Y[off] = v[r] + bi[r] + resid[off];
                }
            }
        }
    }
}

// ---------------------------------------------------------------------------
// MFMA flash attention (unchanged core from round 2). Epilogue now writes
// bf16 attT[b][n][c] (c = h*64+d contiguous) for direct proj-GEMM consumption.
// ---------------------------------------------------------------------------
__global__ __launch_bounds__(256) void attn_mfma(const __bf16* __restrict__ qT,
                                                 const __bf16* __restrict__ kT,
                                                 const __bf16* __restrict__ vB,
                                                 __bf16* __restrict__ attT) {
    const int tid  = threadIdx.x;
    const int w    = tid >> 6;
    const int lane = tid & 63;
    const int quad = lane >> 4;
    const int l16  = lane & 15;
    const int h = blockIdx.y, b = blockIdx.z;
    const int nq0 = blockIdx.x << 7;      // 128 q per wg
    const int qw0 = nq0 + (w << 5);       // 32 q per wave

    __shared__ __bf16 Ks[64][72];         // [key][d], +8 pad -> 2-way alias only
    __shared__ __bf16 Vs[64][72];         // [d][key]
    __shared__ __bf16 Ps[4][32][72];      // per-wave P^T as [q][key]

    const size_t bh = (size_t)b * NH_ + h;
    const __bf16* qTb = qT + bh * ((size_t)N_ * HD_);
    const __bf16* kTb = kT + bh * ((size_t)N_ * HD_);
    const __bf16* vBb = vB + bh * ((size_t)HD_ * N_);

    bf16x8 qf[2][2];
#pragma unroll
    for (int qt = 0; qt < 2; ++qt)
#pragma unroll
        for (int hh = 0; hh < 2; ++hh)
            qf[qt][hh] = *(const bf16x8*)(qTb +
                (size_t)(qw0 + (qt << 4) + l16) * HD_ + (hh << 5) + (quad << 3));

    const f32x4 zero4 = {0.f, 0.f, 0.f, 0.f};
    f32x4 o[4][2];
#pragma unroll
    for (int dt = 0; dt < 4; ++dt) { o[dt][0] = zero4; o[dt][1] = zero4; }
    float m_i[2] = {-1e30f, -1e30f}, l_i[2] = {0.f, 0.f};

    const int sr = tid >> 2;
    const int sc = (tid & 3) << 4;

    for (int it = 0; it < 64; ++it) {
        const int kb = it << 6;
        {
            const float4* ksrc = (const float4*)(kTb + (size_t)(kb + sr) * HD_ + sc);
            const float4* vsrc = (const float4*)(vBb + (size_t)sr * N_ + kb + sc);
            float4 k0 = ksrc[0], k1 = ksrc[1];
            float4 v0 = vsrc[0], v1 = vsrc[1];
            *(float4*)&Ks[sr][sc]     = k0;
            *(float4*)&Ks[sr][sc + 8] = k1;
            *(float4*)&Vs[sr][sc]     = v0;
            *(float4*)&Vs[sr][sc + 8] = v1;
        }
        __syncthreads();

        f32x4 s[4][2];
#pragma unroll
        for (int kt = 0; kt < 4; ++kt) { s[kt][0] = zero4; s[kt][1] = zero4; }
#pragma unroll
        for (int hh = 0; hh < 2; ++hh) {
#pragma unroll
            for (int kt = 0; kt < 4; ++kt) {
                bf16x8 a = *(const bf16x8*)&Ks[(kt << 4) + l16][(hh << 5) + (quad << 3)];
                s[kt][0] = __builtin_amdgcn_mfma_f32_16x16x32_bf16(a, qf[0][hh], s[kt][0], 0, 0, 0);
                s[kt][1] = __builtin_amdgcn_mfma_f32_16x16x32_bf16(a, qf[1][hh], s[kt][1], 0, 0, 0);
            }
        }

#pragma unroll
        for (int qt = 0; qt < 2; ++qt) {
            float mx = s[0][qt][0];
#pragma unroll
            for (int kt = 0; kt < 4; ++kt)
#pragma unroll
                for (int r = 0; r < 4; ++r) mx = fmaxf(mx, s[kt][qt][r]);
            mx = fmaxf(mx, __shfl_xor(mx, 16));
            mx = fmaxf(mx, __shfl_xor(mx, 32));
            float mn = fmaxf(m_i[qt], mx);
            float alpha = EXP2(m_i[qt] - mn);
            m_i[qt] = mn;
            float rs = 0.f;
#pragma unroll
            for (int kt = 0; kt < 4; ++kt)
#pragma unroll
                for (int r = 0; r < 4; ++r) {
                    float pv = EXP2(s[kt][qt][r] - mn);
                    s[kt][qt][r] = pv;
                    rs += pv;
                }
            rs += __shfl_xor(rs, 16);
            rs += __shfl_xor(rs, 32);
            l_i[qt] = l_i[qt] * alpha + rs;
#pragma unroll
            for (int dt = 0; dt < 4; ++dt) o[dt][qt] *= alpha;
#pragma unroll
            for (int kt = 0; kt < 4; ++kt) {
                uint2 pk;
                pk.x = f2bf(s[kt][qt][0]) | (f2bf(s[kt][qt][1]) << 16);
                pk.y = f2bf(s[kt][qt][2]) | (f2bf(s[kt][qt][3]) << 16);
                *(uint2*)&Ps[w][(qt << 4) + l16][(kt << 4) + (quad << 2)] = pk;
            }
        }

#pragma unroll
        for (int hh = 0; hh < 2; ++hh) {
            bf16x8 pf0 = *(const bf16x8*)&Ps[w][l16][(hh << 5) + (quad << 3)];
            bf16x8 pf1 = *(const bf16x8*)&Ps[w][16 + l16][(hh << 5) + (quad << 3)];
#pragma unroll
            for (int dt = 0; dt < 4; ++dt) {
                bf16x8 a = *(const bf16x8*)&Vs[(dt << 4) + l16][(hh << 5) + (quad << 3)];
                o[dt][0] = __builtin_amdgcn_mfma_f32_16x16x32_bf16(a, pf0, o[dt][0], 0, 0, 0);
                o[dt][1] = __builtin_amdgcn_mfma_f32_16x16x32_bf16(a, pf1, o[dt][1], 0, 0, 0);
            }
        }
        __syncthreads();
    }

    // epilogue: attT[b][n][h*64+d] = o/l, bf16, 4 d per uint2
#pragma unroll
    for (int qt = 0; qt < 2; ++qt) {
        float inv = 1.f / l_i[qt];
        int n = qw0 + (qt << 4) + l16;
        __bf16* dst = attT + ((size_t)b * N_ + n) * C_ + h * HD_ + (quad << 2);
#pragma unroll
        for (int dt = 0; dt < 4; ++dt) {
            uint2 pk;
            pk.x = f2bf(o[dt][qt][0] * inv) | (f2bf(o[dt][qt][1] * inv) << 16);
            pk.y = f2bf(o[dt][qt][2] * inv) | (f2bf(o[dt][qt][3] * inv) << 16);
            *(uint2*)(dst + (dt << 4)) = pk;
        }
    }
}

// ---------------------------------------------------------------------------
extern "C" void kernel_launch(void* const* d_in, const int* in_sizes, int n_in,
                              void* d_out, int out_size, void* d_ws, size_t ws_size,
                              hipStream_t stream) {
    const float* x      = (const float*)d_in[0];
    const float* norm_w = (const float*)d_in[1];
    const float* norm_b = (const float*)d_in[2];
    const float* qkv_w  = (const float*)d_in[3];
    const float* qkv_b  = (const float*)d_in[4];
    const float* proj_w = (const float*)d_in[5];
    const float* proj_b = (const float*)d_in[6];
    float* out = (float*)d_out;

    const size_t BCN = (size_t)B_ * C_ * N_;      // 4194304
    float* stats = (float*)d_ws;                  // 64 floats
    __bf16* xnT  = (__bf16*)(stats + 64);         // [b][p][c]
    __bf16* qT   = xnT + BCN;                     // [bh][p][d]
    __bf16* kT   = qT + BCN;                      // [bh][p][d]
    __bf16* vB   = kT + BCN;                      // [bh][d][p]
    __bf16* attT = vB + BCN;                      // [b][n][c]
    __bf16* wq   = attT + BCN;                    // 1536x512
    __bf16* wp   = wq + (size_t)3 * C_ * C_;      // 512x512

    gn_stats<<<B_ * G_, 256, 0, stream>>>(x, stats);
    w2bf<<<(4 * C_ * C_ / 4) / 256, 256, 0, stream>>>(qkv_w, proj_w, wq, wp);
    gn_apply_t<<<dim3(N_ / 64, C_ / 64, B_), 256, 0, stream>>>(
        x, norm_w, norm_b, stats, xnT);
    gemm_bf16<3 * C_, 0><<<dim3(N_ / 128, 3 * C_ / 128, B_), 256, 0, stream>>>(
        wq, xnT, qkv_b, nullptr, qT, kT, vB, nullptr);
    attn_mfma<<<dim3(N_ / 128, NH_, B_), 256, 0, stream>>>(qT, kT, vB, attT);
    gemm_bf16<C_, 1><<<dim3(N_ / 128, C_ / 128, B_), 256, 0, stream>>>(
        wp, attT, proj_b, x, nullptr, nullptr, nullptr, out);
}

// Round 4
// 301.572 us; speedup vs baseline: 5.1775x; 1.1562x over previous
//
#include <hip/hip_runtime.h>
#include <stdint.h>

#define B_   2
#define C_   512
#define N_   4096           // 64*64 pixels
#define G_   8
#define NH_  8
#define HD_  64
#define GRPELEMS ((C_ / G_) * N_)   // 262144 per (b, group)

typedef __bf16 bf16x8 __attribute__((ext_vector_type(8)));
typedef float  f32x4  __attribute__((ext_vector_type(4)));

#if __has_builtin(__builtin_amdgcn_exp2f)
#define EXP2(x) __builtin_amdgcn_exp2f(x)
#else
#define EXP2(x) exp2f(x)
#endif

// fp32 -> bf16 round-to-nearest-even (finite inputs only)
__device__ inline unsigned f2bf(float f) {
    union { float f; unsigned u; } v; v.f = f;
    return (v.u + 0x7FFFu + ((v.u >> 16) & 1u)) >> 16;
}
__device__ inline __bf16 tobf(float f) {
    unsigned short u = (unsigned short)f2bf(f);
    union { unsigned short u; __bf16 b; } c; c.u = u;
    return c.b;
}
// pack hi16(f1):hi16(f0) in ONE v_perm_b32 (truncation to bf16)
__device__ inline unsigned pktrunc(float f0, float f1) {
    return __builtin_amdgcn_perm(__float_as_uint(f1), __float_as_uint(f0),
                                 0x07060302u);
}

// async global->LDS, 16B per lane; LDS dest = wave-uniform base + lane*16
#define GLOAD16(g, l)                                                     \
    __builtin_amdgcn_global_load_lds(                                     \
        (const __attribute__((address_space(1))) unsigned*)(g),           \
        (__attribute__((address_space(3))) unsigned*)(l), 16, 0, 0)

// ---------------------------------------------------------------------------
// GroupNorm stats: one block per (b, group); group = contiguous 256K floats.
// ---------------------------------------------------------------------------
__global__ __launch_bounds__(256) void gn_stats(const float* __restrict__ x,
                                                float* __restrict__ stats) {
    __shared__ float ss[256];
    __shared__ float sq[256];
    const int bg = blockIdx.x;  // 0..15
    const float4* p = (const float4*)(x + (size_t)bg * GRPELEMS);
    float s = 0.f, s2 = 0.f;
    for (int i = threadIdx.x; i < GRPELEMS / 4; i += 256) {
        float4 v = p[i];
        s  += v.x + v.y + v.z + v.w;
        s2 += v.x * v.x + v.y * v.y + v.z * v.z + v.w * v.w;
    }
    ss[threadIdx.x] = s;
    sq[threadIdx.x] = s2;
    __syncthreads();
    for (int st = 128; st > 0; st >>= 1) {
        if (threadIdx.x < st) {
            ss[threadIdx.x] += ss[threadIdx.x + st];
            sq[threadIdx.x] += sq[threadIdx.x + st];
        }
        __syncthreads();
    }
    if (threadIdx.x == 0) {
        const float inv = 1.f / (float)GRPELEMS;
        float mean = ss[0] * inv;
        float var  = sq[0] * inv - mean * mean;
        stats[bg]      = mean;
        stats[16 + bg] = rsqrtf(var + 1e-5f);
    }
}

// ---------------------------------------------------------------------------
// Weight fp32 -> bf16 (qkv_w then proj_w). 4 elems/thread.
// ---------------------------------------------------------------------------
__global__ __launch_bounds__(256) void w2bf(const float* __restrict__ qw,
                                            const float* __restrict__ pw,
                                            __bf16* __restrict__ dq,
                                            __bf16* __restrict__ dp) {
    const int QW4 = (3 * C_ * C_) / 4;   // 196608
    int idx = blockIdx.x * 256 + threadIdx.x;
    float4 v; __bf16* dst; int o;
    if (idx < QW4) { v = ((const float4*)qw)[idx]; dst = dq; o = idx; }
    else           { v = ((const float4*)pw)[idx - QW4]; dst = dp; o = idx - QW4; }
    uint2 pk;
    pk.x = f2bf(v.x) | (f2bf(v.y) << 16);
    pk.y = f2bf(v.z) | (f2bf(v.w) << 16);
    *(uint2*)(dst + (size_t)o * 4) = pk;
}

// ---------------------------------------------------------------------------
// GroupNorm apply + transpose: x[b][c][p] fp32 -> xnT[b][p][c] bf16.
// ---------------------------------------------------------------------------
__global__ __launch_bounds__(256) void gn_apply_t(const float* __restrict__ x,
                                                  const float* __restrict__ w,
                                                  const float* __restrict__ bb,
                                                  const float* __restrict__ stats,
                                                  __bf16* __restrict__ xnT) {
    const int p0 = blockIdx.x << 6, c0 = blockIdx.y << 6, b = blockIdx.z;
    __shared__ __bf16 T[64][76];   // row stride 152 B
    const int tr  = threadIdx.x >> 4;
    const int tc4 = (threadIdx.x & 15) << 2;
    const int bg = b * G_ + (c0 >> 6);
    const float mean = stats[bg], rstd = stats[16 + bg];
    const float* xb = x + ((size_t)b * C_ + c0) * N_ + p0;
#pragma unroll
    for (int cc = tr; cc < 64; cc += 16) {
        int c = c0 + cc;
        float sc = rstd * w[c];
        float sh = bb[c] - mean * sc;
        float4 v = *(const float4*)(xb + (size_t)cc * N_ + tc4);
        T[tc4 + 0][cc] = tobf(v.x * sc + sh);
        T[tc4 + 1][cc] = tobf(v.y * sc + sh);
        T[tc4 + 2][cc] = tobf(v.z * sc + sh);
        T[tc4 + 3][cc] = tobf(v.w * sc + sh);
    }
    __syncthreads();
    __bf16* dst = xnT + ((size_t)b * N_ + p0) * C_ + c0;
#pragma unroll
    for (int pp = tr; pp < 64; pp += 16)
        *(uint2*)(dst + (size_t)pp * C_ + tc4) = *(const uint2*)&T[pp][tc4];
}

// ---------------------------------------------------------------------------
// bf16 MFMA GEMM (unchanged from round 3): C[o][p] = sum_c A[o][c]*Bm[b][p][c]
// ---------------------------------------------------------------------------
template <int M_TOTAL, int EPI>
__global__ __launch_bounds__(256) void gemm_bf16(const __bf16* __restrict__ A,
                                                 const __bf16* __restrict__ Bm,
                                                 const float* __restrict__ bias,
                                                 const float* __restrict__ resid,
                                                 __bf16* __restrict__ qT,
                                                 __bf16* __restrict__ kT,
                                                 __bf16* __restrict__ vB,
                                                 float* __restrict__ Y) {
    const int b  = blockIdx.z;
    const int M0 = blockIdx.y << 7;
    const int N0 = blockIdx.x << 7;
    const int tid = threadIdx.x;
    const int w = tid >> 6, lane = tid & 63;
    const int quad = lane >> 4, l16 = lane & 15;
    const int wr = w >> 1, wc = w & 1;

    __shared__ __bf16 As[128 * 64];
    __shared__ __bf16 Bs[128 * 64];

    const __bf16* Bb = Bm + (size_t)b * ((size_t)N_ * C_);

    const int srow = lane >> 3;
    const int sg   = lane & 7;

    f32x4 acc[4][4];
#pragma unroll
    for (int mt = 0; mt < 4; ++mt)
#pragma unroll
        for (int nt = 0; nt < 4; ++nt) acc[mt][nt] = (f32x4){0.f, 0.f, 0.f, 0.f};

    for (int k0 = 0; k0 < C_; k0 += 64) {
        __syncthreads();
#pragma unroll
        for (int i = 0; i < 4; ++i) {
            int r  = (w << 5) + (i << 3) + srow;
            int gc = ((sg ^ (r & 7)) << 3);
            const __bf16* ga = A  + (size_t)(M0 + r) * C_ + k0 + gc;
            const __bf16* gb = Bb + (size_t)(N0 + r) * C_ + k0 + gc;
            GLOAD16(ga, As + (((w << 2) + i) << 9));
            GLOAD16(gb, Bs + (((w << 2) + i) << 9));
        }
        __syncthreads();

#pragma unroll
        for (int kk = 0; kk < 2; ++kk) {
            bf16x8 af[4], bfr[4];
            const int gk = (kk << 2) + quad;
#pragma unroll
            for (int mt = 0; mt < 4; ++mt) {
                int m = (wr << 6) + (mt << 4) + l16;
                af[mt] = *(const bf16x8*)&As[(m << 6) + ((gk ^ (m & 7)) << 3)];
            }
#pragma unroll
            for (int nt = 0; nt < 4; ++nt) {
                int n = (wc << 6) + (nt << 4) + l16;
                bfr[nt] = *(const bf16x8*)&Bs[(n << 6) + ((gk ^ (n & 7)) << 3)];
            }
#pragma unroll
            for (int mt = 0; mt < 4; ++mt)
#pragma unroll
                for (int nt = 0; nt < 4; ++nt)
                    acc[mt][nt] = __builtin_amdgcn_mfma_f32_16x16x32_bf16(
                        af[mt], bfr[nt], acc[mt][nt], 0, 0, 0);
        }
    }

    if (EPI == 0) {
        const int t = M0 >> 9;
        const float sc = (t == 0) ? (0.125f * 1.44269504f) : 1.f;
#pragma unroll
        for (int mt = 0; mt < 4; ++mt) {
            const int o0 = M0 + (wr << 6) + (mt << 4) + (quad << 2);
            const int h  = (o0 >> 6) & 7;
            const int d0 = o0 & 63;
            const size_t bh = (size_t)b * NH_ + h;
            float bi[4];
#pragma unroll
            for (int r = 0; r < 4; ++r) bi[r] = bias[o0 + r];
            if (t < 2) {
                __bf16* dst = (t == 0 ? qT : kT) + (bh * N_) * HD_ + d0;
#pragma unroll
                for (int nt = 0; nt < 4; ++nt) {
                    int p = N0 + (wc << 6) + (nt << 4) + l16;
                    f32x4 v = acc[mt][nt];
                    uint2 pk;
                    pk.x = f2bf((v[0] + bi[0]) * sc) | (f2bf((v[1] + bi[1]) * sc) << 16);
                    pk.y = f2bf((v[2] + bi[2]) * sc) | (f2bf((v[3] + bi[3]) * sc) << 16);
                    *(uint2*)(dst + (size_t)p * HD_) = pk;
                }
            } else {
                __bf16* dst = vB + bh * ((size_t)HD_ * N_);
#pragma unroll
                for (int nt = 0; nt < 4; ++nt) {
                    int p = N0 + (wc << 6) + (nt << 4) + l16;
                    f32x4 v = acc[mt][nt];
#pragma unroll
                    for (int r = 0; r < 4; ++r)
                        dst[(size_t)(d0 + r) * N_ + p] = tobf(v[r] + bi[r]);
                }
            }
        }
    } else {
#pragma unroll
        for (int mt = 0; mt < 4; ++mt) {
            const int o0 = M0 + (wr << 6) + (mt << 4) + (quad << 2);
            float bi[4];
#pragma unroll
            for (int r = 0; r < 4; ++r) bi[r] = bias[o0 + r];
#pragma unroll
            for (int nt = 0; nt < 4; ++nt) {
                int p = N0 + (wc << 6) + (nt << 4) + l16;
                f32x4 v = acc[mt][nt];
#pragma unroll
                for (int r = 0; r < 4; ++r) {
                    size_t off = ((size_t)b * C_ + o0 + r) * N_ + p;
                    Y[off] = v[r] + bi[r] + resid[off];
                }
            }
        }
    }
}

// ---------------------------------------------------------------------------
// MFMA flash attention v2:
//  - no online max (scores bounded; plain exp2 accumulation = exact softmax)
//  - l via ones-row MFMA (V tile rows 64..79: row64=1, rest 0)
//  - P packed with v_perm truncation (1 instr / 2 vals)
//  - double-buffered K/V staged by global_load_lds w=16, XOR-swizzled 16B
//    granules; single barrier per iter, prefetch issued right after it.
//  Row strides are 128B (==0 mod 32 banks) so the XOR swizzle makes every
//  LDS access pattern perfectly bank-balanced (zero excess conflicts).
// ---------------------------------------------------------------------------
__global__ __launch_bounds__(256) void attn_mfma(const __bf16* __restrict__ qT,
                                                 const __bf16* __restrict__ kT,
                                                 const __bf16* __restrict__ vB,
                                                 __bf16* __restrict__ attT) {
    const int tid  = threadIdx.x;
    const int w    = tid >> 6;
    const int lane = tid & 63;
    const int quad = lane >> 4;
    const int l16  = lane & 15;
    const int l7   = l16 & 7;
    const int h = blockIdx.y, b = blockIdx.z;
    const int qw0 = (blockIdx.x << 7) + (w << 5);   // 32 q per wave

    __shared__ __bf16 Ks[2][64][64];   // [buf][key][d]   swizzled granules
    __shared__ __bf16 Vs[2][80][64];   // [buf][d][key]; rows 64..79: ones trick
    __shared__ __bf16 Ps[4][32][64];   // per-wave P^T [q][key], 8B-granule swz

    const size_t bh = (size_t)b * NH_ + h;
    const __bf16* qTb = qT + bh * ((size_t)N_ * HD_);
    const __bf16* kTb = kT + bh * ((size_t)N_ * HD_);
    const __bf16* vBb = vB + bh * ((size_t)HD_ * N_);

    // ones/zeros rows 64..79 of both V buffers (uniform rows: swizzle no-op)
    {
        int r = tid >> 3;                 // 0..31: buf = r>>4, row = 64+(r&15)
        int c = (tid & 7) << 3;
        __bf16 val = ((r & 15) == 0) ? (__bf16)1.0f : (__bf16)0.0f;
        __bf16* dst = &Vs[r >> 4][64 + (r & 15)][c];
#pragma unroll
        for (int u = 0; u < 8; ++u) dst[u] = val;
    }

    // Q fragments: persistent across the whole k-loop (q pre-scaled)
    bf16x8 qf[2][2];
#pragma unroll
    for (int qt = 0; qt < 2; ++qt)
#pragma unroll
        for (int hh = 0; hh < 2; ++hh)
            qf[qt][hh] = *(const bf16x8*)(qTb +
                (size_t)(qw0 + (qt << 4) + l16) * HD_ + (hh << 5) + (quad << 3));

    const int rrel = lane >> 3;          // 0..7
    const int gsw  = ((lane & 7) ^ rrel) << 3;  // swizzled source elem offset

    // stage 64-key K and V tiles for iteration `it` into buffer `buf`
    auto stage = [&](int it, int buf) {
        const int kb = it << 6;
#pragma unroll
        for (int c = 0; c < 2; ++c) {
            const int rb = (w << 4) + (c << 3);   // rowbase, multiple of 8
            const __bf16* gk = kTb + (size_t)(kb + rb + rrel) * HD_ + gsw;
            GLOAD16(gk, &Ks[buf][rb][0]);
            const __bf16* gv = vBb + (size_t)(rb + rrel) * N_ + kb + gsw;
            GLOAD16(gv, &Vs[buf][rb][0]);
        }
    };

    const f32x4 zero4 = {0.f, 0.f, 0.f, 0.f};
    f32x4 o[5][2];
#pragma unroll
    for (int dt = 0; dt < 5; ++dt) { o[dt][0] = zero4; o[dt][1] = zero4; }

    stage(0, 0);

    for (int it = 0; it < 64; ++it) {
        const int cur = it & 1;
        __syncthreads();            // drains vmcnt: buf[cur] staged; buf[cur^1] free
        if (it < 63) stage(it + 1, cur ^ 1);

        // S^T[key][q] = K . Q^T
        f32x4 s[4][2];
#pragma unroll
        for (int kt = 0; kt < 4; ++kt) { s[kt][0] = zero4; s[kt][1] = zero4; }
#pragma unroll
        for (int hh = 0; hh < 2; ++hh) {
#pragma unroll
            for (int kt = 0; kt < 4; ++kt) {
                bf16x8 a = *(const bf16x8*)&Ks[cur][(kt << 4) + l16]
                                              [(((hh << 2) + quad) ^ l7) << 3];
                s[kt][0] = __builtin_amdgcn_mfma_f32_16x16x32_bf16(a, qf[0][hh], s[kt][0], 0, 0, 0);
                s[kt][1] = __builtin_amdgcn_mfma_f32_16x16x32_bf16(a, qf[1][hh], s[kt][1], 0, 0, 0);
            }
        }

        // P = exp2(S) (no max subtraction), pack to bf16 via v_perm truncation
#pragma unroll
        for (int qt = 0; qt < 2; ++qt)
#pragma unroll
            for (int kt = 0; kt < 4; ++kt) {
                f32x4 sv = s[kt][qt];
                float e0 = EXP2(sv[0]), e1 = EXP2(sv[1]);
                float e2 = EXP2(sv[2]), e3 = EXP2(sv[3]);
                uint2 pk;
                pk.x = pktrunc(e0, e1);
                pk.y = pktrunc(e2, e3);
                // row (qt*16+l16), 8B granule (4kt+quad) ^ (2*l7)
                *(uint2*)&Ps[w][(qt << 4) + l16]
                            [(((kt << 2) + quad) ^ (l7 << 1)) << 2] = pk;
            }

        // O^T[d][q] += V^T . P^T ; dt==4 is the ones-row tile accumulating l
#pragma unroll
        for (int hh = 0; hh < 2; ++hh) {
            bf16x8 pf0 = *(const bf16x8*)&Ps[w][l16]
                          [(((hh << 3) + (quad << 1)) ^ (l7 << 1)) << 2];
            bf16x8 pf1 = *(const bf16x8*)&Ps[w][16 + l16]
                          [(((hh << 3) + (quad << 1)) ^ (l7 << 1)) << 2];
#pragma unroll
            for (int dt = 0; dt < 5; ++dt) {
                bf16x8 a = *(const bf16x8*)&Vs[cur][(dt << 4) + l16]
                                              [(((hh << 2) + quad) ^ l7) << 3];
                o[dt][0] = __builtin_amdgcn_mfma_f32_16x16x32_bf16(a, pf0, o[dt][0], 0, 0, 0);
                o[dt][1] = __builtin_amdgcn_mfma_f32_16x16x32_bf16(a, pf1, o[dt][1], 0, 0, 0);
            }
        }
    }

    // l lives in o[4][qt][0] on quad==0 lanes (D row 0), col = l16
    float lq[2];
    lq[0] = __shfl(o[4][0][0], l16, 64);
    lq[1] = __shfl(o[4][1][0], l16, 64);

    // epilogue: attT[b][n][h*64+d] = o/l, bf16 (RNE)
#pragma unroll
    for (int qt = 0; qt < 2; ++qt) {
        float inv = 1.f / lq[qt];
        int n = qw0 + (qt << 4) + l16;
        __bf16* dst = attT + ((size_t)b * N_ + n) * C_ + h * HD_ + (quad << 2);
#pragma unroll
        for (int dt = 0; dt < 4; ++dt) {
            uint2 pk;
            pk.x = f2bf(o[dt][qt][0] * inv) | (f2bf(o[dt][qt][1] * inv) << 16);
            pk.y = f2bf(o[dt][qt][2] * inv) | (f2bf(o[dt][qt][3] * inv) << 16);
            *(uint2*)(dst + (dt << 4)) = pk;
        }
    }
}

// ---------------------------------------------------------------------------
extern "C" void kernel_launch(void* const* d_in, const int* in_sizes, int n_in,
                              void* d_out, int out_size, void* d_ws, size_t ws_size,
                              hipStream_t stream) {
    const float* x      = (const float*)d_in[0];
    const float* norm_w = (const float*)d_in[1];
    const float* norm_b = (const float*)d_in[2];
    const float* qkv_w  = (const float*)d_in[3];
    const float* qkv_b  = (const float*)d_in[4];
    const float* proj_w = (const float*)d_in[5];
    const float* proj_b = (const float*)d_in[6];
    float* out = (float*)d_out;

    const size_t BCN = (size_t)B_ * C_ * N_;      // 4194304
    float* stats = (float*)d_ws;                  // 64 floats
    __bf16* xnT  = (__bf16*)(stats + 64);         // [b][p][c]
    __bf16* qT   = xnT + BCN;                     // [bh][p][d]
    __bf16* kT   = qT + BCN;                      // [bh][p][d]
    __bf16* vB   = kT + BCN;                      // [bh][d][p]
    __bf16* attT = vB + BCN;                      // [b][n][c]
    __bf16* wq   = attT + BCN;                    // 1536x512
    __bf16* wp   = wq + (size_t)3 * C_ * C_;      // 512x512

    gn_stats<<<B_ * G_, 256, 0, stream>>>(x, stats);
    w2bf<<<(4 * C_ * C_ / 4) / 256, 256, 0, stream>>>(qkv_w, proj_w, wq, wp);
    gn_apply_t<<<dim3(N_ / 64, C_ / 64, B_), 256, 0, stream>>>(
        x, norm_w, norm_b, stats, xnT);
    gemm_bf16<3 * C_, 0><<<dim3(N_ / 128, 3 * C_ / 128, B_), 256, 0, stream>>>(
        wq, xnT, qkv_b, nullptr, qT, kT, vB, nullptr);
    attn_mfma<<<dim3(N_ / 128, NH_, B_), 256, 0, stream>>>(qT, kT, vB, attT);
    gemm_bf16<C_, 1><<<dim3(N_ / 128, C_ / 128, B_), 256, 0, stream>>>(
        wp, attT, proj_b, x, nullptr, nullptr, nullptr, out);
}

// Round 5
// 230.590 us; speedup vs baseline: 6.7713x; 1.3078x over previous
//
#include <hip/hip_runtime.h>
#include <stdint.h>

#define B_   2
#define C_   512
#define N_   4096           // 64*64 pixels
#define G_   8
#define NH_  8
#define HD_  64
#define GRPELEMS ((C_ / G_) * N_)   // 262144 per (b, group)
#define NCHUNK 64                   // partial-reduce chunks per (b, group)

typedef __bf16 bf16x8 __attribute__((ext_vector_type(8)));
typedef float  f32x4  __attribute__((ext_vector_type(4)));

#if __has_builtin(__builtin_amdgcn_exp2f)
#define EXP2(x) __builtin_amdgcn_exp2f(x)
#else
#define EXP2(x) exp2f(x)
#endif

// fp32 -> bf16 round-to-nearest-even (finite inputs only)
__device__ inline unsigned f2bf(float f) {
    union { float f; unsigned u; } v; v.f = f;
    return (v.u + 0x7FFFu + ((v.u >> 16) & 1u)) >> 16;
}
__device__ inline __bf16 tobf(float f) {
    unsigned short u = (unsigned short)f2bf(f);
    union { unsigned short u; __bf16 b; } c; c.u = u;
    return c.b;
}
// pack hi16(f1):hi16(f0) in ONE v_perm_b32 (truncation to bf16)
__device__ inline unsigned pktrunc(float f0, float f1) {
    return __builtin_amdgcn_perm(__float_as_uint(f1), __float_as_uint(f0),
                                 0x07060302u);
}

// async global->LDS, 16B per lane; LDS dest = wave-uniform base + lane*16
#define GLOAD16(g, l)                                                     \
    __builtin_amdgcn_global_load_lds(                                     \
        (const __attribute__((address_space(1))) unsigned*)(g),           \
        (__attribute__((address_space(3))) unsigned*)(l), 16, 0, 0)

// ---------------------------------------------------------------------------
// GroupNorm partial stats: 1024 blocks, each reduces one 4096-elem chunk.
// blk = bg*64 + chunk; chunks are contiguous in memory (bg-major layout).
// ---------------------------------------------------------------------------
__global__ __launch_bounds__(256) void gn_part(const float* __restrict__ x,
                                               float* __restrict__ psum,
                                               float* __restrict__ psq) {
    const int blk = blockIdx.x;                 // 0..1023
    const float4* p = (const float4*)x + (size_t)blk * 1024;
    const int t = threadIdx.x;
    float s = 0.f, s2 = 0.f;
#pragma unroll
    for (int i = 0; i < 4; ++i) {
        float4 v = p[t + (i << 8)];
        s  += v.x + v.y + v.z + v.w;
        s2 += v.x * v.x + v.y * v.y + v.z * v.z + v.w * v.w;
    }
#pragma unroll
    for (int off = 1; off < 64; off <<= 1) {
        s  += __shfl_xor(s, off);
        s2 += __shfl_xor(s2, off);
    }
    __shared__ float rs[4], rq[4];
    if ((t & 63) == 0) { rs[t >> 6] = s; rq[t >> 6] = s2; }
    __syncthreads();
    if (t == 0) {
        psum[blk] = rs[0] + rs[1] + rs[2] + rs[3];
        psq[blk]  = rq[0] + rq[1] + rq[2] + rq[3];
    }
}

// ---------------------------------------------------------------------------
// Weight fp32 -> bf16 (qkv_w then proj_w). 4 elems/thread.
// ---------------------------------------------------------------------------
__global__ __launch_bounds__(256) void w2bf(const float* __restrict__ qw,
                                            const float* __restrict__ pw,
                                            __bf16* __restrict__ dq,
                                            __bf16* __restrict__ dp) {
    const int QW4 = (3 * C_ * C_) / 4;   // 196608
    int idx = blockIdx.x * 256 + threadIdx.x;
    float4 v; __bf16* dst; int o;
    if (idx < QW4) { v = ((const float4*)qw)[idx]; dst = dq; o = idx; }
    else           { v = ((const float4*)pw)[idx - QW4]; dst = dp; o = idx - QW4; }
    uint2 pk;
    pk.x = f2bf(v.x) | (f2bf(v.y) << 16);
    pk.y = f2bf(v.z) | (f2bf(v.w) << 16);
    *(uint2*)(dst + (size_t)o * 4) = pk;
}

// ---------------------------------------------------------------------------
// GroupNorm finalize + apply + transpose: x[b][c][p] fp32 -> xnT[b][p][c] bf16.
// Prologue reduces this group's 64 partial sums (L2-hit) -> mean/rstd.
// ---------------------------------------------------------------------------
__global__ __launch_bounds__(256) void gn_apply_t(const float* __restrict__ x,
                                                  const float* __restrict__ w,
                                                  const float* __restrict__ bb,
                                                  const float* __restrict__ psum,
                                                  const float* __restrict__ psq,
                                                  __bf16* __restrict__ xnT) {
    const int p0 = blockIdx.x << 6, c0 = blockIdx.y << 6, b = blockIdx.z;
    __shared__ __bf16 T[64][76];   // row stride 152 B
    __shared__ float red[2 * NCHUNK];
    __shared__ float smr[2];
    const int tid = threadIdx.x;
    const int bg = b * G_ + (c0 >> 6);

    if (tid < NCHUNK)            red[tid] = psum[bg * NCHUNK + tid];
    else if (tid < 2 * NCHUNK)   red[tid] = psq[bg * NCHUNK + tid - NCHUNK];
    __syncthreads();
    if (tid == 0) {
        float s = 0.f, q = 0.f;
#pragma unroll
        for (int i = 0; i < NCHUNK; ++i) { s += red[i]; q += red[NCHUNK + i]; }
        const float inv = 1.f / (float)GRPELEMS;
        float mean = s * inv;
        float var  = q * inv - mean * mean;
        smr[0] = mean;
        smr[1] = rsqrtf(var + 1e-5f);
    }
    __syncthreads();
    const float mean = smr[0], rstd = smr[1];

    const int tr  = tid >> 4;
    const int tc4 = (tid & 15) << 2;
    const float* xb = x + ((size_t)b * C_ + c0) * N_ + p0;
#pragma unroll
    for (int cc = tr; cc < 64; cc += 16) {
        int c = c0 + cc;
        float sc = rstd * w[c];
        float sh = bb[c] - mean * sc;
        float4 v = *(const float4*)(xb + (size_t)cc * N_ + tc4);
        T[tc4 + 0][cc] = tobf(v.x * sc + sh);
        T[tc4 + 1][cc] = tobf(v.y * sc + sh);
        T[tc4 + 2][cc] = tobf(v.z * sc + sh);
        T[tc4 + 3][cc] = tobf(v.w * sc + sh);
    }
    __syncthreads();
    __bf16* dst = xnT + ((size_t)b * N_ + p0) * C_ + c0;
#pragma unroll
    for (int pp = tr; pp < 64; pp += 16)
        *(uint2*)(dst + (size_t)pp * C_ + tc4) = *(const uint2*)&T[pp][tc4];
}

// ---------------------------------------------------------------------------
// bf16 MFMA GEMM (unchanged): C[o][p] = sum_c A[o][c]*Bm[b][p][c]
// ---------------------------------------------------------------------------
template <int M_TOTAL, int EPI>
__global__ __launch_bounds__(256) void gemm_bf16(const __bf16* __restrict__ A,
                                                 const __bf16* __restrict__ Bm,
                                                 const float* __restrict__ bias,
                                                 const float* __restrict__ resid,
                                                 __bf16* __restrict__ qT,
                                                 __bf16* __restrict__ kT,
                                                 __bf16* __restrict__ vB,
                                                 float* __restrict__ Y) {
    const int b  = blockIdx.z;
    const int M0 = blockIdx.y << 7;
    const int N0 = blockIdx.x << 7;
    const int tid = threadIdx.x;
    const int w = tid >> 6, lane = tid & 63;
    const int quad = lane >> 4, l16 = lane & 15;
    const int wr = w >> 1, wc = w & 1;

    __shared__ __bf16 As[128 * 64];
    __shared__ __bf16 Bs[128 * 64];

    const __bf16* Bb = Bm + (size_t)b * ((size_t)N_ * C_);

    const int srow = lane >> 3;
    const int sg   = lane & 7;

    f32x4 acc[4][4];
#pragma unroll
    for (int mt = 0; mt < 4; ++mt)
#pragma unroll
        for (int nt = 0; nt < 4; ++nt) acc[mt][nt] = (f32x4){0.f, 0.f, 0.f, 0.f};

    for (int k0 = 0; k0 < C_; k0 += 64) {
        __syncthreads();
#pragma unroll
        for (int i = 0; i < 4; ++i) {
            int r  = (w << 5) + (i << 3) + srow;
            int gc = ((sg ^ (r & 7)) << 3);
            const __bf16* ga = A  + (size_t)(M0 + r) * C_ + k0 + gc;
            const __bf16* gb = Bb + (size_t)(N0 + r) * C_ + k0 + gc;
            GLOAD16(ga, As + (((w << 2) + i) << 9));
            GLOAD16(gb, Bs + (((w << 2) + i) << 9));
        }
        __syncthreads();

#pragma unroll
        for (int kk = 0; kk < 2; ++kk) {
            bf16x8 af[4], bfr[4];
            const int gk = (kk << 2) + quad;
#pragma unroll
            for (int mt = 0; mt < 4; ++mt) {
                int m = (wr << 6) + (mt << 4) + l16;
                af[mt] = *(const bf16x8*)&As[(m << 6) + ((gk ^ (m & 7)) << 3)];
            }
#pragma unroll
            for (int nt = 0; nt < 4; ++nt) {
                int n = (wc << 6) + (nt << 4) + l16;
                bfr[nt] = *(const bf16x8*)&Bs[(n << 6) + ((gk ^ (n & 7)) << 3)];
            }
#pragma unroll
            for (int mt = 0; mt < 4; ++mt)
#pragma unroll
                for (int nt = 0; nt < 4; ++nt)
                    acc[mt][nt] = __builtin_amdgcn_mfma_f32_16x16x32_bf16(
                        af[mt], bfr[nt], acc[mt][nt], 0, 0, 0);
        }
    }

    if (EPI == 0) {
        const int t = M0 >> 9;
        const float sc = (t == 0) ? (0.125f * 1.44269504f) : 1.f;
#pragma unroll
        for (int mt = 0; mt < 4; ++mt) {
            const int o0 = M0 + (wr << 6) + (mt << 4) + (quad << 2);
            const int h  = (o0 >> 6) & 7;
            const int d0 = o0 & 63;
            const size_t bh = (size_t)b * NH_ + h;
            float bi[4];
#pragma unroll
            for (int r = 0; r < 4; ++r) bi[r] = bias[o0 + r];
            if (t < 2) {
                __bf16* dst = (t == 0 ? qT : kT) + (bh * N_) * HD_ + d0;
#pragma unroll
                for (int nt = 0; nt < 4; ++nt) {
                    int p = N0 + (wc << 6) + (nt << 4) + l16;
                    f32x4 v = acc[mt][nt];
                    uint2 pk;
                    pk.x = f2bf((v[0] + bi[0]) * sc) | (f2bf((v[1] + bi[1]) * sc) << 16);
                    pk.y = f2bf((v[2] + bi[2]) * sc) | (f2bf((v[3] + bi[3]) * sc) << 16);
                    *(uint2*)(dst + (size_t)p * HD_) = pk;
                }
            } else {
                __bf16* dst = vB + bh * ((size_t)HD_ * N_);
#pragma unroll
                for (int nt = 0; nt < 4; ++nt) {
                    int p = N0 + (wc << 6) + (nt << 4) + l16;
                    f32x4 v = acc[mt][nt];
#pragma unroll
                    for (int r = 0; r < 4; ++r)
                        dst[(size_t)(d0 + r) * N_ + p] = tobf(v[r] + bi[r]);
                }
            }
        }
    } else {
#pragma unroll
        for (int mt = 0; mt < 4; ++mt) {
            const int o0 = M0 + (wr << 6) + (mt << 4) + (quad << 2);
            float bi[4];
#pragma unroll
            for (int r = 0; r < 4; ++r) bi[r] = bias[o0 + r];
#pragma unroll
            for (int nt = 0; nt < 4; ++nt) {
                int p = N0 + (wc << 6) + (nt << 4) + l16;
                f32x4 v = acc[mt][nt];
#pragma unroll
                for (int r = 0; r < 4; ++r) {
                    size_t off = ((size_t)b * C_ + o0 + r) * N_ + p;
                    Y[off] = v[r] + bi[r] + resid[off];
                }
            }
        }
    }
}

// ---------------------------------------------------------------------------
// MFMA flash attention v2 (unchanged from round 4).
// ---------------------------------------------------------------------------
__global__ __launch_bounds__(256) void attn_mfma(const __bf16* __restrict__ qT,
                                                 const __bf16* __restrict__ kT,
                                                 const __bf16* __restrict__ vB,
                                                 __bf16* __restrict__ attT) {
    const int tid  = threadIdx.x;
    const int w    = tid >> 6;
    const int lane = tid & 63;
    const int quad = lane >> 4;
    const int l16  = lane & 15;
    const int l7   = l16 & 7;
    const int h = blockIdx.y, b = blockIdx.z;
    const int qw0 = (blockIdx.x << 7) + (w << 5);   // 32 q per wave

    __shared__ __bf16 Ks[2][64][64];   // [buf][key][d]   swizzled granules
    __shared__ __bf16 Vs[2][80][64];   // [buf][d][key]; rows 64..79: ones trick
    __shared__ __bf16 Ps[4][32][64];   // per-wave P^T [q][key], 8B-granule swz

    const size_t bh = (size_t)b * NH_ + h;
    const __bf16* qTb = qT + bh * ((size_t)N_ * HD_);
    const __bf16* kTb = kT + bh * ((size_t)N_ * HD_);
    const __bf16* vBb = vB + bh * ((size_t)HD_ * N_);

    // ones/zeros rows 64..79 of both V buffers (uniform rows: swizzle no-op)
    {
        int r = tid >> 3;                 // 0..31: buf = r>>4, row = 64+(r&15)
        int c = (tid & 7) << 3;
        __bf16 val = ((r & 15) == 0) ? (__bf16)1.0f : (__bf16)0.0f;
        __bf16* dst = &Vs[r >> 4][64 + (r & 15)][c];
#pragma unroll
        for (int u = 0; u < 8; ++u) dst[u] = val;
    }

    // Q fragments: persistent across the whole k-loop (q pre-scaled)
    bf16x8 qf[2][2];
#pragma unroll
    for (int qt = 0; qt < 2; ++qt)
#pragma unroll
        for (int hh = 0; hh < 2; ++hh)
            qf[qt][hh] = *(const bf16x8*)(qTb +
                (size_t)(qw0 + (qt << 4) + l16) * HD_ + (hh << 5) + (quad << 3));

    const int rrel = lane >> 3;          // 0..7
    const int gsw  = ((lane & 7) ^ rrel) << 3;  // swizzled source elem offset

    // stage 64-key K and V tiles for iteration `it` into buffer `buf`
    auto stage = [&](int it, int buf) {
        const int kb = it << 6;
#pragma unroll
        for (int c = 0; c < 2; ++c) {
            const int rb = (w << 4) + (c << 3);   // rowbase, multiple of 8
            const __bf16* gk = kTb + (size_t)(kb + rb + rrel) * HD_ + gsw;
            GLOAD16(gk, &Ks[buf][rb][0]);
            const __bf16* gv = vBb + (size_t)(rb + rrel) * N_ + kb + gsw;
            GLOAD16(gv, &Vs[buf][rb][0]);
        }
    };

    const f32x4 zero4 = {0.f, 0.f, 0.f, 0.f};
    f32x4 o[5][2];
#pragma unroll
    for (int dt = 0; dt < 5; ++dt) { o[dt][0] = zero4; o[dt][1] = zero4; }

    stage(0, 0);

    for (int it = 0; it < 64; ++it) {
        const int cur = it & 1;
        __syncthreads();            // drains vmcnt: buf[cur] staged; buf[cur^1] free
        if (it < 63) stage(it + 1, cur ^ 1);

        // S^T[key][q] = K . Q^T
        f32x4 s[4][2];
#pragma unroll
        for (int kt = 0; kt < 4; ++kt) { s[kt][0] = zero4; s[kt][1] = zero4; }
#pragma unroll
        for (int hh = 0; hh < 2; ++hh) {
#pragma unroll
            for (int kt = 0; kt < 4; ++kt) {
                bf16x8 a = *(const bf16x8*)&Ks[cur][(kt << 4) + l16]
                                              [(((hh << 2) + quad) ^ l7) << 3];
                s[kt][0] = __builtin_amdgcn_mfma_f32_16x16x32_bf16(a, qf[0][hh], s[kt][0], 0, 0, 0);
                s[kt][1] = __builtin_amdgcn_mfma_f32_16x16x32_bf16(a, qf[1][hh], s[kt][1], 0, 0, 0);
            }
        }

        // P = exp2(S) (no max subtraction), pack to bf16 via v_perm truncation
#pragma unroll
        for (int qt = 0; qt < 2; ++qt)
#pragma unroll
            for (int kt = 0; kt < 4; ++kt) {
                f32x4 sv = s[kt][qt];
                float e0 = EXP2(sv[0]), e1 = EXP2(sv[1]);
                float e2 = EXP2(sv[2]), e3 = EXP2(sv[3]);
                uint2 pk;
                pk.x = pktrunc(e0, e1);
                pk.y = pktrunc(e2, e3);
                *(uint2*)&Ps[w][(qt << 4) + l16]
                            [(((kt << 2) + quad) ^ (l7 << 1)) << 2] = pk;
            }

        // O^T[d][q] += V^T . P^T ; dt==4 is the ones-row tile accumulating l
#pragma unroll
        for (int hh = 0; hh < 2; ++hh) {
            bf16x8 pf0 = *(const bf16x8*)&Ps[w][l16]
                          [(((hh << 3) + (quad << 1)) ^ (l7 << 1)) << 2];
            bf16x8 pf1 = *(const bf16x8*)&Ps[w][16 + l16]
                          [(((hh << 3) + (quad << 1)) ^ (l7 << 1)) << 2];
#pragma unroll
            for (int dt = 0; dt < 5; ++dt) {
                bf16x8 a = *(const bf16x8*)&Vs[cur][(dt << 4) + l16]
                                              [(((hh << 2) + quad) ^ l7) << 3];
                o[dt][0] = __builtin_amdgcn_mfma_f32_16x16x32_bf16(a, pf0, o[dt][0], 0, 0, 0);
                o[dt][1] = __builtin_amdgcn_mfma_f32_16x16x32_bf16(a, pf1, o[dt][1], 0, 0, 0);
            }
        }
    }

    // l lives in o[4][qt][0] on quad==0 lanes (D row 0), col = l16
    float lq[2];
    lq[0] = __shfl(o[4][0][0], l16, 64);
    lq[1] = __shfl(o[4][1][0], l16, 64);

    // epilogue: attT[b][n][h*64+d] = o/l, bf16 (RNE)
#pragma unroll
    for (int qt = 0; qt < 2; ++qt) {
        float inv = 1.f / lq[qt];
        int n = qw0 + (qt << 4) + l16;
        __bf16* dst = attT + ((size_t)b * N_ + n) * C_ + h * HD_ + (quad << 2);
#pragma unroll
        for (int dt = 0; dt < 4; ++dt) {
            uint2 pk;
            pk.x = f2bf(o[dt][qt][0] * inv) | (f2bf(o[dt][qt][1] * inv) << 16);
            pk.y = f2bf(o[dt][qt][2] * inv) | (f2bf(o[dt][qt][3] * inv) << 16);
            *(uint2*)(dst + (dt << 4)) = pk;
        }
    }
}

// ---------------------------------------------------------------------------
extern "C" void kernel_launch(void* const* d_in, const int* in_sizes, int n_in,
                              void* d_out, int out_size, void* d_ws, size_t ws_size,
                              hipStream_t stream) {
    const float* x      = (const float*)d_in[0];
    const float* norm_w = (const float*)d_in[1];
    const float* norm_b = (const float*)d_in[2];
    const float* qkv_w  = (const float*)d_in[3];
    const float* qkv_b  = (const float*)d_in[4];
    const float* proj_w = (const float*)d_in[5];
    const float* proj_b = (const float*)d_in[6];
    float* out = (float*)d_out;

    const size_t BCN = (size_t)B_ * C_ * N_;      // 4194304
    float* psum  = (float*)d_ws;                  // 1024 floats
    float* psq   = psum + 1024;                   // 1024 floats
    __bf16* xnT  = (__bf16*)(psq + 1024);         // [b][p][c]
    __bf16* qT   = xnT + BCN;                     // [bh][p][d]
    __bf16* kT   = qT + BCN;                      // [bh][p][d]
    __bf16* vB   = kT + BCN;                      // [bh][d][p]
    __bf16* attT = vB + BCN;                      // [b][n][c]
    __bf16* wq   = attT + BCN;                    // 1536x512
    __bf16* wp   = wq + (size_t)3 * C_ * C_;      // 512x512

    gn_part<<<B_ * G_ * NCHUNK, 256, 0, stream>>>(x, psum, psq);
    w2bf<<<(4 * C_ * C_ / 4) / 256, 256, 0, stream>>>(qkv_w, proj_w, wq, wp);
    gn_apply_t<<<dim3(N_ / 64, C_ / 64, B_), 256, 0, stream>>>(
        x, norm_w, norm_b, psum, psq, xnT);
    gemm_bf16<3 * C_, 0><<<dim3(N_ / 128, 3 * C_ / 128, B_), 256, 0, stream>>>(
        wq, xnT, qkv_b, nullptr, qT, kT, vB, nullptr);
    attn_mfma<<<dim3(N_ / 128, NH_, B_), 256, 0, stream>>>(qT, kT, vB, attT);
    gemm_bf16<C_, 1><<<dim3(N_ / 128, C_ / 128, B_), 256, 0, stream>>>(
        wp, attT, proj_b, x, nullptr, nullptr, nullptr, out);
}